// Round 13
// baseline (735.927 us; speedup 1.0000x reference)
//
#include <hip/hip_runtime.h>
#include <stdint.h>

// Problem constants
#define B_    32
#define T_    256
#define CD    100
#define BD    100
#define TD    20
#define LIN   200
#define HD    200
#define INDIM 420
#define G4    800   // 4*H

typedef __attribute__((ext_vector_type(8))) short bfrag8;   // 8 bf16 (4 VGPRs)
typedef __attribute__((ext_vector_type(4))) float f32x4v;   // MFMA accumulator

static __device__ __forceinline__ unsigned short f2bf(float f) {
  unsigned u = __float_as_uint(f);
  u = u + 0x7fffu + ((u >> 16) & 1u);   // RTNE
  return (unsigned short)(u >> 16);
}
static __device__ __forceinline__ float bf2f(unsigned short s) {
  return __uint_as_float(((unsigned)s) << 16);
}
static __device__ __forceinline__ float tanhx(float x) {
  return 1.0f - 2.0f * __builtin_amdgcn_rcpf(1.0f + __builtin_amdgcn_exp2f(x * 2.8853900817779268f));
}
static __device__ __forceinline__ float clamp40(float x) {
  return fminf(fmaxf(x, -40.0f), 40.0f);
}

static __device__ __forceinline__ void mk_hilo(float4 a, float4 b, bfrag8& hi, bfrag8& lo) {
  float q[8] = {a.x, a.y, a.z, a.w, b.x, b.y, b.z, b.w};
  #pragma unroll
  for (int j = 0; j < 8; ++j) {
    unsigned short h = f2bf(q[j]);
    hi[j] = (short)h;
    lo[j] = (short)f2bf(q[j] - bf2f(h));
  }
}
static __device__ __forceinline__ bfrag8 mk_hi(float4 a, float4 b) {
  bfrag8 r;
  float q[8] = {a.x, a.y, a.z, a.w, b.x, b.y, b.z, b.w};
  #pragma unroll
  for (int j = 0; j < 8; ++j) r[j] = (short)f2bf(q[j]);
  return r;
}

// ---------------------------------------------------------------------------
// Kernel W: pre-split fc_w and Wih_{l,r} into hi/lo bf16 in MFMA fragment layout
// frag layout: elem i = ((nt*KT + kt)*64 + lane)*8 + j ;
//   n = nt*16 + (lane&15), k = kt*32 + (lane>>4)*8 + j
// Wih rows are PERMUTED: frag col n' maps to original row (n'&3)*200 + (n'>>2)
// ---------------------------------------------------------------------------
__global__ void presplit_kernel(const float* __restrict__ fc_w,
                                const float* __restrict__ Wih_l,
                                const float* __restrict__ Wih_r,
                                unsigned short* __restrict__ fcw_hi,
                                unsigned short* __restrict__ fcw_lo,
                                unsigned short* __restrict__ wih_hi,
                                unsigned short* __restrict__ wih_lo) {
  int tid = blockIdx.x * blockDim.x + threadIdx.x;
  int stride = gridDim.x * blockDim.x;
  for (int i = tid; i < 13 * 14 * 512; i += stride) {
    int j = i & 7, l = (i >> 3) & 63, f = i >> 9;
    int kt = f % 14, nt = f / 14;
    int n = nt * 16 + (l & 15);
    int k = kt * 32 + ((l >> 4) << 3) + j;
    float v = (n < LIN && k < INDIM) ? fc_w[n * INDIM + k] : 0.0f;
    unsigned short h = f2bf(v);
    fcw_hi[i] = h;
    fcw_lo[i] = f2bf(v - bf2f(h));
  }
  for (int d = 0; d < 2; ++d) {
    const float* W = d ? Wih_r : Wih_l;
    unsigned short* oh = wih_hi + (size_t)d * 179200;
    unsigned short* ol = wih_lo + (size_t)d * 179200;
    for (int i = tid; i < 50 * 7 * 512; i += stride) {
      int j = i & 7, l = (i >> 3) & 63, f = i >> 9;
      int kt = f % 7, nt = f / 7;
      int np = nt * 16 + (l & 15);                 // permuted col n'
      int no = (np & 3) * 200 + (np >> 2);         // original Wih row
      int k = kt * 32 + ((l >> 4) << 3) + j;
      float v = (k < LIN) ? W[no * LIN + k] : 0.0f;
      unsigned short h = f2bf(v);
      oh[i] = h;
      ol[i] = f2bf(v - bf2f(h));
    }
  }
}

// ---------------------------------------------------------------------------
// Kernel A: embedding gather + concat(420) + FC + tanh -> x [2*8192][200] f32
// ---------------------------------------------------------------------------
__global__ __launch_bounds__(256) void fc_kernel(
    const int* __restrict__ chars, const int* __restrict__ left_bichar,
    const int* __restrict__ right_bichar, const int* __restrict__ extchars,
    const int* __restrict__ extleft, const int* __restrict__ extright,
    const int* __restrict__ ctype,
    const float* __restrict__ E_char, const float* __restrict__ E_extchar,
    const float* __restrict__ E_bichar, const float* __restrict__ E_extbichar,
    const float* __restrict__ E_ctype, const float* __restrict__ fc_b,
    const unsigned short* __restrict__ fcw_hi, const unsigned short* __restrict__ fcw_lo,
    float* __restrict__ x) {
  __shared__ __align__(16) float feat[32 * 452];
  int rb = blockIdx.x;            // dir*256 + t
  int dir = rb >> 8;
  int t = rb & 255;
  int tid = threadIdx.x;
  const int* bi  = dir ? right_bichar : left_bichar;
  const int* ebi = dir ? extright : extleft;

  for (int cc = tid; cc < 32 * 113; cc += 256) {
    int lr = cc / 113, kc = cc - lr * 113;
    int k = kc << 2;
    float4 v = make_float4(0.f, 0.f, 0.f, 0.f);
    if (k < INDIM) {
      int id; const float* tab; int kk; int wdt;
      if (k < 100)      { id = chars[lr * T_ + t];    tab = E_char;      kk = k;       wdt = 100; }
      else if (k < 200) { id = extchars[lr * T_ + t]; tab = E_extchar;   kk = k - 100; wdt = 100; }
      else if (k < 300) { id = bi[lr * T_ + t];       tab = E_bichar;    kk = k - 200; wdt = 100; }
      else if (k < 400) { id = ebi[lr * T_ + t];      tab = E_extbichar; kk = k - 300; wdt = 100; }
      else              { id = ctype[lr * T_ + t];    tab = E_ctype;     kk = k - 400; wdt = 20;  }
      v = *reinterpret_cast<const float4*>(tab + (size_t)id * wdt + kk);
    }
    *reinterpret_cast<float4*>(&feat[lr * 452 + k]) = v;
  }
  __syncthreads();

  int w = tid >> 6, l = tid & 63;
  int lrow = l & 15, lk8 = (l >> 4) << 3;
  f32x4v acc[8];
  #pragma unroll
  for (int i = 0; i < 8; ++i) acc[i] = (f32x4v){0.f, 0.f, 0.f, 0.f};

  for (int kt = 0; kt < 14; ++kt) {
    bfrag8 ah[2], al[2];
    #pragma unroll
    for (int mt = 0; mt < 2; ++mt) {
      const float* fp = &feat[(mt * 16 + lrow) * 452 + kt * 32 + lk8];
      float4 v0 = *reinterpret_cast<const float4*>(fp);
      float4 v1 = *reinterpret_cast<const float4*>(fp + 4);
      mk_hilo(v0, v1, ah[mt], al[mt]);
    }
    #pragma unroll
    for (int s = 0; s < 4; ++s) {
      int nt = w + (s << 2);
      if (nt < 13) {
        size_t fo = ((size_t)(nt * 14 + kt) * 64 + l) * 8;
        bfrag8 bh = *reinterpret_cast<const bfrag8*>(fcw_hi + fo);
        bfrag8 bl = *reinterpret_cast<const bfrag8*>(fcw_lo + fo);
        #pragma unroll
        for (int mt = 0; mt < 2; ++mt) {
          acc[s * 2 + mt] = __builtin_amdgcn_mfma_f32_16x16x32_bf16(ah[mt], bh, acc[s * 2 + mt], 0, 0, 0);
          acc[s * 2 + mt] = __builtin_amdgcn_mfma_f32_16x16x32_bf16(al[mt], bh, acc[s * 2 + mt], 0, 0, 0);
          acc[s * 2 + mt] = __builtin_amdgcn_mfma_f32_16x16x32_bf16(ah[mt], bl, acc[s * 2 + mt], 0, 0, 0);
        }
      }
    }
  }
  int r0 = rb * 32;
  #pragma unroll
  for (int s = 0; s < 4; ++s) {
    int nt = w + (s << 2);
    if (nt < 13) {
      int n = nt * 16 + lrow;
      if (n < LIN) {
        float bias = fc_b[n];
        #pragma unroll
        for (int mt = 0; mt < 2; ++mt) {
          #pragma unroll
          for (int rr = 0; rr < 4; ++rr) {
            int row = mt * 16 + ((l >> 4) << 2) + rr;
            x[(size_t)(r0 + row) * LIN + n] = tanhx(acc[s * 2 + mt][rr] + bias);
          }
        }
      }
    }
  }
}

// ---------------------------------------------------------------------------
// Kernel B: pre = x @ Wih'.T + b'  (PERMUTED cols n'), written in step-slice
// order:  pre[(((dh*256 + t)*50 + tau)*64 + lane)*4 + g]
//   dh = dir*2 + half; tau = hcol>>2; lane = b + 16*(hcol&3); g = gate.
//   (reader: lane l of tile tau -> cell (b = l&15, hcol = 4*tau + (l>>4)))
// ---------------------------------------------------------------------------
__global__ __launch_bounds__(512) void xwih_kernel(
    const float* __restrict__ x, const unsigned short* __restrict__ wih_hi,
    const unsigned short* __restrict__ wih_lo, const float* __restrict__ b_l,
    const float* __restrict__ b_r, float* __restrict__ pre) {
  int bid = blockIdx.x;             // 640 = 2 * 64 * 5
  int dir = (bid >= 320) ? 1 : 0;
  int rem = bid - dir * 320;
  int rbm = rem / 5, nb = rem - rbm * 5;
  int m0 = rbm * 128, n0 = nb * 160;
  int tid = threadIdx.x, w = tid >> 6, l = tid & 63;
  int lrow = l & 15, lk8 = (l >> 4) << 3;
  const float* xd = x + (size_t)dir * 8192 * LIN;
  const unsigned short* wh = wih_hi + (size_t)dir * 179200;
  const unsigned short* wl = wih_lo + (size_t)dir * 179200;
  const float* bias = dir ? b_r : b_l;

  f32x4v acc[10];
  #pragma unroll
  for (int i = 0; i < 10; ++i) acc[i] = (f32x4v){0.f, 0.f, 0.f, 0.f};

  int row = m0 + w * 16 + lrow;
  for (int kt = 0; kt < 7; ++kt) {
    int kb = kt * 32 + lk8;
    bfrag8 ah = {0,0,0,0,0,0,0,0}, al = {0,0,0,0,0,0,0,0};
    if (kb <= 192) {
      const float* fp = xd + (size_t)row * LIN + kb;
      float4 v0 = *reinterpret_cast<const float4*>(fp);
      float4 v1 = *reinterpret_cast<const float4*>(fp + 4);
      mk_hilo(v0, v1, ah, al);
    }
    #pragma unroll
    for (int nt = 0; nt < 10; ++nt) {
      int ntg = nb * 10 + nt;
      size_t fo = ((size_t)(ntg * 7 + kt) * 64 + l) * 8;
      bfrag8 bh = *reinterpret_cast<const bfrag8*>(wh + fo);
      bfrag8 bl = *reinterpret_cast<const bfrag8*>(wl + fo);
      acc[nt] = __builtin_amdgcn_mfma_f32_16x16x32_bf16(ah, bh, acc[nt], 0, 0, 0);
      acc[nt] = __builtin_amdgcn_mfma_f32_16x16x32_bf16(al, bh, acc[nt], 0, 0, 0);
      acc[nt] = __builtin_amdgcn_mfma_f32_16x16x32_bf16(ah, bl, acc[nt], 0, 0, 0);
    }
  }
  #pragma unroll
  for (int nt = 0; nt < 10; ++nt) {
    int n = n0 + nt * 16 + lrow;                    // permuted col n'
    float bb = bias[(n & 3) * 200 + (n >> 2)];      // original bias row
    int hcol = n >> 2, g = n & 3;
    int tau = hcol >> 2;
    int lhi = hcol & 3;
    #pragma unroll
    for (int rr = 0; rr < 4; ++rr) {
      int r2 = m0 + w * 16 + ((l >> 4) << 2) + rr;  // global row = t*32 + b32
      int t = r2 >> 5, b32 = r2 & 31;
      int hf2 = b32 >> 4, b = b32 & 15;
      int lane = b + 16 * lhi;
      size_t dst = ((((size_t)(dir * 2 + hf2) * 256 + t) * 50 + tau) * 64 + lane) * 4 + g;
      pre[dst] = acc[nt][rr] + bb;
    }
  }
}

// ---------------------------------------------------------------------------
// Kernel R: recurrence, 4 blocks = (dir, batch-half), 512 thr = 8 waves.
// r9 structure EXACT (best measured: 578 us) minus s_setprio (m190: setprio
// is neutral-to-negative on barrier-synced lockstep waves).
// Per-tile interleave: {ds_read pre; 7 MFMAs; fused cell; stores} -- cell(i)
// overlaps MFMAs(i+1..) on separate pipes. hf[7] hoisted per step.
// Whh' tiles 0..47 in Breg[6][7]; tiles 48,49 in LDS whx. pre staged via
// global_load_lds into dbuf pbuf one step ahead; EXACT per-wave vmcnt
// (never waits on scatter stores): w<2: 7+7+7 -> vmcnt(14); w>=2: vmcnt(12).
// ---------------------------------------------------------------------------
__global__ __launch_bounds__(512, 2) void lstm_kernel(
    const float* __restrict__ pre, const float* __restrict__ Whh_l,
    const float* __restrict__ Whh_r, float* __restrict__ out) {
  __shared__ __align__(16) unsigned short hbufA[3584];   // [kt:7][lane:64][j:8] bf16
  __shared__ __align__(16) unsigned short hbufB[3584];
  __shared__ __align__(16) unsigned short whx[7168];     // tiles 48,49 A-frags
  __shared__ __align__(16) float pbuf0[12800];           // pre slice dbuf (51.2KB x2)
  __shared__ __align__(16) float pbuf1[12800];

  int bi = blockIdx.x;
  int dir = bi >> 1, half = bi & 1;
  const float* Whh = dir ? Whh_r : Whh_l;
  int tid = threadIdx.x, w = tid >> 6, l = tid & 63;
  int lrow = l & 15, lk8 = (l >> 4) << 3;

  // --- register-resident Whh' A-frags: tiles tau = w + 8i, i<6 (0..47) ---
  bfrag8 Breg[6][7];
  #pragma unroll
  for (int i = 0; i < 6; ++i) {
    int np = (w + 8 * i) * 16 + lrow;
    int no = (np & 3) * 200 + (np >> 2);
    #pragma unroll
    for (int kt = 0; kt < 7; ++kt) {
      int kb = kt * 32 + lk8;
      bfrag8 bb = {0,0,0,0,0,0,0,0};
      if (kb <= 192) {
        const float* fp = Whh + (size_t)no * HD + kb;
        bb = mk_hi(*reinterpret_cast<const float4*>(fp),
                   *reinterpret_cast<const float4*>(fp + 4));
      }
      Breg[i][kt] = bb;
    }
  }
  // --- LDS tiles 48,49 ---
  for (int e = tid; e < 896; e += 512) {
    int l2 = e & 63, f = e >> 6;          // f = tile*7 + kt, f<14
    int kt = f % 7, tile = f / 7;
    int np = (48 + tile) * 16 + (l2 & 15);
    int no = (np & 3) * 200 + (np >> 2);
    int kb = kt * 32 + ((l2 >> 4) << 3);
    bfrag8 bb = {0,0,0,0,0,0,0,0};
    if (kb <= 192) {
      const float* fp = Whh + (size_t)no * HD + kb;
      bb = mk_hi(*reinterpret_cast<const float4*>(fp),
                 *reinterpret_cast<const float4*>(fp + 4));
    }
    *reinterpret_cast<bfrag8*>(&whx[(size_t)e * 8]) = bb;
  }
  // zero h buffers (h0 = 0; K-pad positions stay zero forever)
  for (int e = tid; e < 896; e += 512) {
    reinterpret_cast<uint64_t*>(hbufA)[e] = 0;
    reinterpret_cast<uint64_t*>(hbufB)[e] = 0;
  }
  float c[7];
  #pragma unroll
  for (int i = 0; i < 7; ++i) c[i] = 0.f;

  // h-frag write slot (bf16, MFMA B layout); kt handled by +i*512
  int hbase = 4 * w + (l >> 4);                       // hcol mod 32
  int hw = (lrow + 16 * ((hbase >> 3) & 3)) * 8 + (hbase & 7);

  // pre source: byte pointer to this lane's 16B (tile offset added per load)
  const char* psrcB = (const char*)(pre
                      + ((size_t)(dir * 2 + half) * 256 + (dir ? 255 : 0)) * 12800)
                    + l * 16;
  const int pstepB = dir ? -51200 : 51200;
  float* outp = out + (size_t)((half * 16 + lrow) * 256 + (dir ? 255 : 0)) * 400
              + dir * 200 + (l >> 4) + 4 * w;
  const int ostep = dir ? -400 : 400;

  __syncthreads();

  // --- prologue: stage step-0 slice into pbuf0, drain ---
  #pragma unroll
  for (int i = 0; i < 6; ++i)
    __builtin_amdgcn_global_load_lds(
        (const __attribute__((address_space(1))) void*)(psrcB + (8 * i + w) * 1024),
        (__attribute__((address_space(3))) void*)(&pbuf0[(8 * i + w) * 256]), 16, 0, 0);
  if (w < 2)
    __builtin_amdgcn_global_load_lds(
        (const __attribute__((address_space(1))) void*)(psrcB + (48 + w) * 1024),
        (__attribute__((address_space(3))) void*)(&pbuf0[(48 + w) * 256]), 16, 0, 0);
  psrcB += pstepB;
  asm volatile("s_waitcnt vmcnt(0)");
  __syncthreads();

  const float NL  = -1.4426950408889634f;   // -log2(e)
  const float N2L = -2.8853900817779268f;   // -2*log2(e)

  auto STEP = [&](const unsigned short* rbuf, unsigned short* wbuf,
                  const float* pcur, float* pnxt) {
    // --- A: stage next step's pre slice into pnxt (async, background) ---
    #pragma unroll
    for (int i = 0; i < 6; ++i)
      __builtin_amdgcn_global_load_lds(
          (const __attribute__((address_space(1))) void*)(psrcB + (8 * i + w) * 1024),
          (__attribute__((address_space(3))) void*)(pnxt + (8 * i + w) * 256), 16, 0, 0);
    if (w < 2)
      __builtin_amdgcn_global_load_lds(
          (const __attribute__((address_space(1))) void*)(psrcB + (48 + w) * 1024),
          (__attribute__((address_space(3))) void*)(pnxt + (48 + w) * 256), 16, 0, 0);
    psrcB += pstepB;
    // --- wait: this step's slice landed in pcur (exact; never waits stores) ---
    __builtin_amdgcn_sched_barrier(0x1 | 0x2 | 0x4 | 0x8);
    if (w < 2) { asm volatile("s_waitcnt vmcnt(14)"); }
    else       { asm volatile("s_waitcnt vmcnt(12)"); }
    __builtin_amdgcn_sched_barrier(0x1 | 0x2 | 0x4 | 0x8);
    // --- hoist h fragments to registers (7 x ds_read_b128) ---
    bfrag8 hf[7];
    #pragma unroll
    for (int kt = 0; kt < 7; ++kt)
      hf[kt] = *reinterpret_cast<const bfrag8*>(&rbuf[kt * 512 + l * 8]);
    // --- per-tile: MFMA chain then cell; cell(i) overlaps MFMAs(i+1..) ---
    #pragma unroll
    for (int i = 0; i < 7; ++i) {
      if (i < 6 || w < 2) {
        int tau = (i < 6) ? (8 * i + w) : (48 + w);
        f32x4v a = *reinterpret_cast<const f32x4v*>(pcur + tau * 256 + l * 4);
        #pragma unroll
        for (int kt = 0; kt < 7; ++kt) {
          bfrag8 bb;
          if (i < 6) bb = Breg[i][kt];
          else       bb = *reinterpret_cast<const bfrag8*>(&whx[(w * 7 + kt) * 512 + l * 8]);
          a = __builtin_amdgcn_mfma_f32_16x16x32_bf16(bb, hf[kt], a, 0, 0, 0);
        }
        // fused cell
        float u  = __builtin_amdgcn_exp2f(clamp40(a[1] * NL));
        float v  = __builtin_amdgcn_exp2f(clamp40(a[0] * NL));
        float Wt = __builtin_amdgcn_exp2f(clamp40(a[2] * N2L));
        float y  = __builtin_amdgcn_exp2f(clamp40(a[3] * NL));
        float pu = 1.f + u, pv = 1.f + v, pw = 1.f + Wt, py = 1.f + y;
        float P  = pv * pw;
        float r1 = __builtin_amdgcn_rcpf(pu * P);
        float cn = (c[i] * P + pu * (1.f - Wt)) * r1;
        c[i] = cn;
        float Z  = __builtin_amdgcn_exp2f(clamp40(cn * N2L));
        float h  = (1.f - Z) * __builtin_amdgcn_rcpf(py * (1.f + Z));
        outp[32 * i] = h;
        wbuf[hw + i * 512] = f2bf(h);
      }
    }
    outp += ostep;
    // --- E: barrier; memory pinned, reg-only ops may cross ---
    __builtin_amdgcn_sched_barrier(0x1 | 0x2 | 0x4 | 0x8);
    asm volatile("s_waitcnt lgkmcnt(0)");
    __builtin_amdgcn_s_barrier();
    __builtin_amdgcn_sched_barrier(0x1 | 0x2 | 0x4 | 0x8);
  };

  for (int it = 0; it < 128; ++it) {
    STEP(hbufA, hbufB, pbuf0, pbuf1);
    STEP(hbufB, hbufA, pbuf1, pbuf0);
  }
}

// ---------------------------------------------------------------------------
extern "C" void kernel_launch(void* const* d_in, const int* in_sizes, int n_in,
                              void* d_out, int out_size, void* d_ws, size_t ws_size,
                              hipStream_t stream) {
  (void)in_sizes; (void)n_in; (void)out_size; (void)ws_size;
  const int* chars        = (const int*)d_in[0];
  const int* left_bichar  = (const int*)d_in[1];
  const int* right_bichar = (const int*)d_in[2];
  const int* extchars     = (const int*)d_in[3];
  const int* extleft      = (const int*)d_in[4];
  const int* extright     = (const int*)d_in[5];
  const int* ctype        = (const int*)d_in[6];
  const float* E_char      = (const float*)d_in[7];
  const float* E_extchar   = (const float*)d_in[8];
  const float* E_bichar    = (const float*)d_in[9];
  const float* E_extbichar = (const float*)d_in[10];
  const float* E_ctype     = (const float*)d_in[11];
  const float* fc_w  = (const float*)d_in[12];
  const float* fc_b  = (const float*)d_in[13];
  const float* Wih_l = (const float*)d_in[14];
  const float* Whh_l = (const float*)d_in[15];
  const float* b_l   = (const float*)d_in[16];
  const float* Wih_r = (const float*)d_in[17];
  const float* Whh_r = (const float*)d_in[18];
  const float* b_r   = (const float*)d_in[19];
  float* out = (float*)d_out;
  char* ws = (char*)d_ws;

  float* x   = (float*)(ws);                        // 13,107,200 B
  float* pre = (float*)(ws + 13107200);             // 52,428,800 B
  unsigned short* fcw_hi = (unsigned short*)(ws + 65536000);   // 186,368
  unsigned short* fcw_lo = (unsigned short*)(ws + 65722368);   // 186,368
  unsigned short* wih_hi = (unsigned short*)(ws + 65908736);   // 716,800
  unsigned short* wih_lo = (unsigned short*)(ws + 66625536);   // 716,800

  presplit_kernel<<<256, 256, 0, stream>>>(fc_w, Wih_l, Wih_r, fcw_hi, fcw_lo, wih_hi, wih_lo);
  fc_kernel<<<512, 256, 0, stream>>>(chars, left_bichar, right_bichar, extchars,
                                     extleft, extright, ctype, E_char, E_extchar,
                                     E_bichar, E_extbichar, E_ctype, fc_b,
                                     fcw_hi, fcw_lo, x);
  xwih_kernel<<<640, 512, 0, stream>>>(x, wih_hi, wih_lo, b_l, b_r, pre);
  lstm_kernel<<<4, 512, 0, stream>>>(pre, Whh_l, Whh_r, out);
}

// Round 14
// 663.498 us; speedup vs baseline: 1.1092x; 1.1092x over previous
//
#include <hip/hip_runtime.h>
#include <stdint.h>

// Problem constants
#define B_    32
#define T_    256
#define CD    100
#define BD    100
#define TD    20
#define LIN   200
#define HD    200
#define INDIM 420
#define G4    800   // 4*H

typedef __attribute__((ext_vector_type(8))) short bfrag8;   // 8 bf16 (4 VGPRs)
typedef __attribute__((ext_vector_type(4))) float f32x4v;   // MFMA accumulator

static __device__ __forceinline__ unsigned short f2bf(float f) {
  unsigned u = __float_as_uint(f);
  u = u + 0x7fffu + ((u >> 16) & 1u);   // RTNE
  return (unsigned short)(u >> 16);
}
static __device__ __forceinline__ float bf2f(unsigned short s) {
  return __uint_as_float(((unsigned)s) << 16);
}
static __device__ __forceinline__ float tanhx(float x) {
  return 1.0f - 2.0f * __builtin_amdgcn_rcpf(1.0f + __builtin_amdgcn_exp2f(x * 2.8853900817779268f));
}
static __device__ __forceinline__ float clamp40(float x) {
  return fminf(fmaxf(x, -40.0f), 40.0f);
}

static __device__ __forceinline__ void mk_hilo(float4 a, float4 b, bfrag8& hi, bfrag8& lo) {
  float q[8] = {a.x, a.y, a.z, a.w, b.x, b.y, b.z, b.w};
  #pragma unroll
  for (int j = 0; j < 8; ++j) {
    unsigned short h = f2bf(q[j]);
    hi[j] = (short)h;
    lo[j] = (short)f2bf(q[j] - bf2f(h));
  }
}
static __device__ __forceinline__ bfrag8 mk_hi(float4 a, float4 b) {
  bfrag8 r;
  float q[8] = {a.x, a.y, a.z, a.w, b.x, b.y, b.z, b.w};
  #pragma unroll
  for (int j = 0; j < 8; ++j) r[j] = (short)f2bf(q[j]);
  return r;
}

// ---------------------------------------------------------------------------
// Kernel W: pre-split fc_w and Wih_{l,r} into hi/lo bf16 in MFMA fragment layout
// frag layout: elem i = ((nt*KT + kt)*64 + lane)*8 + j ;
//   n = nt*16 + (lane&15), k = kt*32 + (lane>>4)*8 + j
// Wih rows are PERMUTED: frag col n' maps to original row (n'&3)*200 + (n'>>2)
// ---------------------------------------------------------------------------
__global__ void presplit_kernel(const float* __restrict__ fc_w,
                                const float* __restrict__ Wih_l,
                                const float* __restrict__ Wih_r,
                                unsigned short* __restrict__ fcw_hi,
                                unsigned short* __restrict__ fcw_lo,
                                unsigned short* __restrict__ wih_hi,
                                unsigned short* __restrict__ wih_lo) {
  int tid = blockIdx.x * blockDim.x + threadIdx.x;
  int stride = gridDim.x * blockDim.x;
  for (int i = tid; i < 13 * 14 * 512; i += stride) {
    int j = i & 7, l = (i >> 3) & 63, f = i >> 9;
    int kt = f % 14, nt = f / 14;
    int n = nt * 16 + (l & 15);
    int k = kt * 32 + ((l >> 4) << 3) + j;
    float v = (n < LIN && k < INDIM) ? fc_w[n * INDIM + k] : 0.0f;
    unsigned short h = f2bf(v);
    fcw_hi[i] = h;
    fcw_lo[i] = f2bf(v - bf2f(h));
  }
  for (int d = 0; d < 2; ++d) {
    const float* W = d ? Wih_r : Wih_l;
    unsigned short* oh = wih_hi + (size_t)d * 179200;
    unsigned short* ol = wih_lo + (size_t)d * 179200;
    for (int i = tid; i < 50 * 7 * 512; i += stride) {
      int j = i & 7, l = (i >> 3) & 63, f = i >> 9;
      int kt = f % 7, nt = f / 7;
      int np = nt * 16 + (l & 15);                 // permuted col n'
      int no = (np & 3) * 200 + (np >> 2);         // original Wih row
      int k = kt * 32 + ((l >> 4) << 3) + j;
      float v = (k < LIN) ? W[no * LIN + k] : 0.0f;
      unsigned short h = f2bf(v);
      oh[i] = h;
      ol[i] = f2bf(v - bf2f(h));
    }
  }
}

// ---------------------------------------------------------------------------
// Kernel A: embedding gather + concat(420) + FC + tanh -> x [2*8192][200] f32
// ---------------------------------------------------------------------------
__global__ __launch_bounds__(256) void fc_kernel(
    const int* __restrict__ chars, const int* __restrict__ left_bichar,
    const int* __restrict__ right_bichar, const int* __restrict__ extchars,
    const int* __restrict__ extleft, const int* __restrict__ extright,
    const int* __restrict__ ctype,
    const float* __restrict__ E_char, const float* __restrict__ E_extchar,
    const float* __restrict__ E_bichar, const float* __restrict__ E_extbichar,
    const float* __restrict__ E_ctype, const float* __restrict__ fc_b,
    const unsigned short* __restrict__ fcw_hi, const unsigned short* __restrict__ fcw_lo,
    float* __restrict__ x) {
  __shared__ __align__(16) float feat[32 * 452];
  int rb = blockIdx.x;            // dir*256 + t
  int dir = rb >> 8;
  int t = rb & 255;
  int tid = threadIdx.x;
  const int* bi  = dir ? right_bichar : left_bichar;
  const int* ebi = dir ? extright : extleft;

  for (int cc = tid; cc < 32 * 113; cc += 256) {
    int lr = cc / 113, kc = cc - lr * 113;
    int k = kc << 2;
    float4 v = make_float4(0.f, 0.f, 0.f, 0.f);
    if (k < INDIM) {
      int id; const float* tab; int kk; int wdt;
      if (k < 100)      { id = chars[lr * T_ + t];    tab = E_char;      kk = k;       wdt = 100; }
      else if (k < 200) { id = extchars[lr * T_ + t]; tab = E_extchar;   kk = k - 100; wdt = 100; }
      else if (k < 300) { id = bi[lr * T_ + t];       tab = E_bichar;    kk = k - 200; wdt = 100; }
      else if (k < 400) { id = ebi[lr * T_ + t];      tab = E_extbichar; kk = k - 300; wdt = 100; }
      else              { id = ctype[lr * T_ + t];    tab = E_ctype;     kk = k - 400; wdt = 20;  }
      v = *reinterpret_cast<const float4*>(tab + (size_t)id * wdt + kk);
    }
    *reinterpret_cast<float4*>(&feat[lr * 452 + k]) = v;
  }
  __syncthreads();

  int w = tid >> 6, l = tid & 63;
  int lrow = l & 15, lk8 = (l >> 4) << 3;
  f32x4v acc[8];
  #pragma unroll
  for (int i = 0; i < 8; ++i) acc[i] = (f32x4v){0.f, 0.f, 0.f, 0.f};

  for (int kt = 0; kt < 14; ++kt) {
    bfrag8 ah[2], al[2];
    #pragma unroll
    for (int mt = 0; mt < 2; ++mt) {
      const float* fp = &feat[(mt * 16 + lrow) * 452 + kt * 32 + lk8];
      float4 v0 = *reinterpret_cast<const float4*>(fp);
      float4 v1 = *reinterpret_cast<const float4*>(fp + 4);
      mk_hilo(v0, v1, ah[mt], al[mt]);
    }
    #pragma unroll
    for (int s = 0; s < 4; ++s) {
      int nt = w + (s << 2);
      if (nt < 13) {
        size_t fo = ((size_t)(nt * 14 + kt) * 64 + l) * 8;
        bfrag8 bh = *reinterpret_cast<const bfrag8*>(fcw_hi + fo);
        bfrag8 bl = *reinterpret_cast<const bfrag8*>(fcw_lo + fo);
        #pragma unroll
        for (int mt = 0; mt < 2; ++mt) {
          acc[s * 2 + mt] = __builtin_amdgcn_mfma_f32_16x16x32_bf16(ah[mt], bh, acc[s * 2 + mt], 0, 0, 0);
          acc[s * 2 + mt] = __builtin_amdgcn_mfma_f32_16x16x32_bf16(al[mt], bh, acc[s * 2 + mt], 0, 0, 0);
          acc[s * 2 + mt] = __builtin_amdgcn_mfma_f32_16x16x32_bf16(ah[mt], bl, acc[s * 2 + mt], 0, 0, 0);
        }
      }
    }
  }
  int r0 = rb * 32;
  #pragma unroll
  for (int s = 0; s < 4; ++s) {
    int nt = w + (s << 2);
    if (nt < 13) {
      int n = nt * 16 + lrow;
      if (n < LIN) {
        float bias = fc_b[n];
        #pragma unroll
        for (int mt = 0; mt < 2; ++mt) {
          #pragma unroll
          for (int rr = 0; rr < 4; ++rr) {
            int row = mt * 16 + ((l >> 4) << 2) + rr;
            x[(size_t)(r0 + row) * LIN + n] = tanhx(acc[s * 2 + mt][rr] + bias);
          }
        }
      }
    }
  }
}

// ---------------------------------------------------------------------------
// Kernel B: pre = x @ Wih'.T + b'  (PERMUTED cols n'), written in step-slice
// order:  pre[(((dh*256 + t)*50 + tau)*64 + lane)*4 + g]
//   dh = dir*2 + half; tau = hcol>>2; lane = b + 16*(hcol&3); g = gate.
//   (reader: lane l of tile tau -> cell (b = l&15, hcol = 4*tau + (l>>4)))
// ---------------------------------------------------------------------------
__global__ __launch_bounds__(512) void xwih_kernel(
    const float* __restrict__ x, const unsigned short* __restrict__ wih_hi,
    const unsigned short* __restrict__ wih_lo, const float* __restrict__ b_l,
    const float* __restrict__ b_r, float* __restrict__ pre) {
  int bid = blockIdx.x;             // 640 = 2 * 64 * 5
  int dir = (bid >= 320) ? 1 : 0;
  int rem = bid - dir * 320;
  int rbm = rem / 5, nb = rem - rbm * 5;
  int m0 = rbm * 128, n0 = nb * 160;
  int tid = threadIdx.x, w = tid >> 6, l = tid & 63;
  int lrow = l & 15, lk8 = (l >> 4) << 3;
  const float* xd = x + (size_t)dir * 8192 * LIN;
  const unsigned short* wh = wih_hi + (size_t)dir * 179200;
  const unsigned short* wl = wih_lo + (size_t)dir * 179200;
  const float* bias = dir ? b_r : b_l;

  f32x4v acc[10];
  #pragma unroll
  for (int i = 0; i < 10; ++i) acc[i] = (f32x4v){0.f, 0.f, 0.f, 0.f};

  int row = m0 + w * 16 + lrow;
  for (int kt = 0; kt < 7; ++kt) {
    int kb = kt * 32 + lk8;
    bfrag8 ah = {0,0,0,0,0,0,0,0}, al = {0,0,0,0,0,0,0,0};
    if (kb <= 192) {
      const float* fp = xd + (size_t)row * LIN + kb;
      float4 v0 = *reinterpret_cast<const float4*>(fp);
      float4 v1 = *reinterpret_cast<const float4*>(fp + 4);
      mk_hilo(v0, v1, ah, al);
    }
    #pragma unroll
    for (int nt = 0; nt < 10; ++nt) {
      int ntg = nb * 10 + nt;
      size_t fo = ((size_t)(ntg * 7 + kt) * 64 + l) * 8;
      bfrag8 bh = *reinterpret_cast<const bfrag8*>(wh + fo);
      bfrag8 bl = *reinterpret_cast<const bfrag8*>(wl + fo);
      acc[nt] = __builtin_amdgcn_mfma_f32_16x16x32_bf16(ah, bh, acc[nt], 0, 0, 0);
      acc[nt] = __builtin_amdgcn_mfma_f32_16x16x32_bf16(al, bh, acc[nt], 0, 0, 0);
      acc[nt] = __builtin_amdgcn_mfma_f32_16x16x32_bf16(ah, bl, acc[nt], 0, 0, 0);
    }
  }
  #pragma unroll
  for (int nt = 0; nt < 10; ++nt) {
    int n = n0 + nt * 16 + lrow;                    // permuted col n'
    float bb = bias[(n & 3) * 200 + (n >> 2)];      // original bias row
    int hcol = n >> 2, g = n & 3;
    int tau = hcol >> 2;
    int lhi = hcol & 3;
    #pragma unroll
    for (int rr = 0; rr < 4; ++rr) {
      int r2 = m0 + w * 16 + ((l >> 4) << 2) + rr;  // global row = t*32 + b32
      int t = r2 >> 5, b32 = r2 & 31;
      int hf2 = b32 >> 4, b = b32 & 15;
      int lane = b + 16 * lhi;
      size_t dst = ((((size_t)(dir * 2 + hf2) * 256 + t) * 50 + tau) * 64 + lane) * 4 + g;
      pre[dst] = acc[nt][rr] + bb;
    }
  }
}

// ---------------------------------------------------------------------------
// Kernel R: recurrence, 4 blocks = (dir, batch-half), 512 thr = 8 waves.
// BYTE-EXACT r9 (best measured: 578 us lstm). s_setprio(1) around the
// compute region is load-bearing (+13%; r13 ablation) -- waves are at
// different phases between barriers (7-vs-6-tile imbalance), so priority
// lets compute-phase waves win issue slots.
// Per-tile interleave: {ds_read pre; 7 MFMAs; fused cell; stores} -- cell(i)
// overlaps MFMAs(i+1..) on separate pipes. hf[7] hoisted per step.
// Whh' tiles 0..47 in Breg[6][7]; tiles 48,49 in LDS whx. pre staged via
// global_load_lds into dbuf pbuf one step ahead; EXACT per-wave vmcnt
// (never waits on scatter stores): w<2: 7+7+7 -> vmcnt(14); w>=2: vmcnt(12).
// ---------------------------------------------------------------------------
__global__ __launch_bounds__(512, 2) void lstm_kernel(
    const float* __restrict__ pre, const float* __restrict__ Whh_l,
    const float* __restrict__ Whh_r, float* __restrict__ out) {
  __shared__ __align__(16) unsigned short hbufA[3584];   // [kt:7][lane:64][j:8] bf16
  __shared__ __align__(16) unsigned short hbufB[3584];
  __shared__ __align__(16) unsigned short whx[7168];     // tiles 48,49 A-frags
  __shared__ __align__(16) float pbuf0[12800];           // pre slice dbuf (51.2KB x2)
  __shared__ __align__(16) float pbuf1[12800];

  int bi = blockIdx.x;
  int dir = bi >> 1, half = bi & 1;
  const float* Whh = dir ? Whh_r : Whh_l;
  int tid = threadIdx.x, w = tid >> 6, l = tid & 63;
  int lrow = l & 15, lk8 = (l >> 4) << 3;

  // --- register-resident Whh' A-frags: tiles tau = w + 8i, i<6 (0..47) ---
  bfrag8 Breg[6][7];
  #pragma unroll
  for (int i = 0; i < 6; ++i) {
    int np = (w + 8 * i) * 16 + lrow;
    int no = (np & 3) * 200 + (np >> 2);
    #pragma unroll
    for (int kt = 0; kt < 7; ++kt) {
      int kb = kt * 32 + lk8;
      bfrag8 bb = {0,0,0,0,0,0,0,0};
      if (kb <= 192) {
        const float* fp = Whh + (size_t)no * HD + kb;
        bb = mk_hi(*reinterpret_cast<const float4*>(fp),
                   *reinterpret_cast<const float4*>(fp + 4));
      }
      Breg[i][kt] = bb;
    }
  }
  // --- LDS tiles 48,49 ---
  for (int e = tid; e < 896; e += 512) {
    int l2 = e & 63, f = e >> 6;          // f = tile*7 + kt, f<14
    int kt = f % 7, tile = f / 7;
    int np = (48 + tile) * 16 + (l2 & 15);
    int no = (np & 3) * 200 + (np >> 2);
    int kb = kt * 32 + ((l2 >> 4) << 3);
    bfrag8 bb = {0,0,0,0,0,0,0,0};
    if (kb <= 192) {
      const float* fp = Whh + (size_t)no * HD + kb;
      bb = mk_hi(*reinterpret_cast<const float4*>(fp),
                 *reinterpret_cast<const float4*>(fp + 4));
    }
    *reinterpret_cast<bfrag8*>(&whx[(size_t)e * 8]) = bb;
  }
  // zero h buffers (h0 = 0; K-pad positions stay zero forever)
  for (int e = tid; e < 896; e += 512) {
    reinterpret_cast<uint64_t*>(hbufA)[e] = 0;
    reinterpret_cast<uint64_t*>(hbufB)[e] = 0;
  }
  float c[7];
  #pragma unroll
  for (int i = 0; i < 7; ++i) c[i] = 0.f;

  // h-frag write slot (bf16, MFMA B layout); kt handled by +i*512
  int hbase = 4 * w + (l >> 4);                       // hcol mod 32
  int hw = (lrow + 16 * ((hbase >> 3) & 3)) * 8 + (hbase & 7);

  // pre source: byte pointer to this lane's 16B (tile offset added per load)
  const char* psrcB = (const char*)(pre
                      + ((size_t)(dir * 2 + half) * 256 + (dir ? 255 : 0)) * 12800)
                    + l * 16;
  const int pstepB = dir ? -51200 : 51200;
  float* outp = out + (size_t)((half * 16 + lrow) * 256 + (dir ? 255 : 0)) * 400
              + dir * 200 + (l >> 4) + 4 * w;
  const int ostep = dir ? -400 : 400;

  __syncthreads();

  // --- prologue: stage step-0 slice into pbuf0, drain ---
  #pragma unroll
  for (int i = 0; i < 6; ++i)
    __builtin_amdgcn_global_load_lds(
        (const __attribute__((address_space(1))) void*)(psrcB + (8 * i + w) * 1024),
        (__attribute__((address_space(3))) void*)(&pbuf0[(8 * i + w) * 256]), 16, 0, 0);
  if (w < 2)
    __builtin_amdgcn_global_load_lds(
        (const __attribute__((address_space(1))) void*)(psrcB + (48 + w) * 1024),
        (__attribute__((address_space(3))) void*)(&pbuf0[(48 + w) * 256]), 16, 0, 0);
  psrcB += pstepB;
  asm volatile("s_waitcnt vmcnt(0)");
  __syncthreads();

  const float NL  = -1.4426950408889634f;   // -log2(e)
  const float N2L = -2.8853900817779268f;   // -2*log2(e)

  auto STEP = [&](const unsigned short* rbuf, unsigned short* wbuf,
                  const float* pcur, float* pnxt) {
    // --- A: stage next step's pre slice into pnxt (async, background) ---
    #pragma unroll
    for (int i = 0; i < 6; ++i)
      __builtin_amdgcn_global_load_lds(
          (const __attribute__((address_space(1))) void*)(psrcB + (8 * i + w) * 1024),
          (__attribute__((address_space(3))) void*)(pnxt + (8 * i + w) * 256), 16, 0, 0);
    if (w < 2)
      __builtin_amdgcn_global_load_lds(
          (const __attribute__((address_space(1))) void*)(psrcB + (48 + w) * 1024),
          (__attribute__((address_space(3))) void*)(pnxt + (48 + w) * 256), 16, 0, 0);
    psrcB += pstepB;
    // --- wait: this step's slice landed in pcur (exact; never waits stores) ---
    __builtin_amdgcn_sched_barrier(0x1 | 0x2 | 0x4 | 0x8);
    if (w < 2) { asm volatile("s_waitcnt vmcnt(14)"); }
    else       { asm volatile("s_waitcnt vmcnt(12)"); }
    __builtin_amdgcn_sched_barrier(0x1 | 0x2 | 0x4 | 0x8);
    // --- hoist h fragments to registers (7 x ds_read_b128) ---
    bfrag8 hf[7];
    #pragma unroll
    for (int kt = 0; kt < 7; ++kt)
      hf[kt] = *reinterpret_cast<const bfrag8*>(&rbuf[kt * 512 + l * 8]);
    // --- per-tile: MFMA chain then cell; cell(i) overlaps MFMAs(i+1..) ---
    __builtin_amdgcn_s_setprio(1);
    #pragma unroll
    for (int i = 0; i < 7; ++i) {
      if (i < 6 || w < 2) {
        int tau = (i < 6) ? (8 * i + w) : (48 + w);
        f32x4v a = *reinterpret_cast<const f32x4v*>(pcur + tau * 256 + l * 4);
        #pragma unroll
        for (int kt = 0; kt < 7; ++kt) {
          bfrag8 bb;
          if (i < 6) bb = Breg[i][kt];
          else       bb = *reinterpret_cast<const bfrag8*>(&whx[(w * 7 + kt) * 512 + l * 8]);
          a = __builtin_amdgcn_mfma_f32_16x16x32_bf16(bb, hf[kt], a, 0, 0, 0);
        }
        // fused cell
        float u  = __builtin_amdgcn_exp2f(clamp40(a[1] * NL));
        float v  = __builtin_amdgcn_exp2f(clamp40(a[0] * NL));
        float Wt = __builtin_amdgcn_exp2f(clamp40(a[2] * N2L));
        float y  = __builtin_amdgcn_exp2f(clamp40(a[3] * NL));
        float pu = 1.f + u, pv = 1.f + v, pw = 1.f + Wt, py = 1.f + y;
        float P  = pv * pw;
        float r1 = __builtin_amdgcn_rcpf(pu * P);
        float cn = (c[i] * P + pu * (1.f - Wt)) * r1;
        c[i] = cn;
        float Z  = __builtin_amdgcn_exp2f(clamp40(cn * N2L));
        float h  = (1.f - Z) * __builtin_amdgcn_rcpf(py * (1.f + Z));
        outp[32 * i] = h;
        wbuf[hw + i * 512] = f2bf(h);
      }
    }
    __builtin_amdgcn_s_setprio(0);
    outp += ostep;
    // --- E: barrier; memory pinned, reg-only ops may cross ---
    __builtin_amdgcn_sched_barrier(0x1 | 0x2 | 0x4 | 0x8);
    asm volatile("s_waitcnt lgkmcnt(0)");
    __builtin_amdgcn_s_barrier();
    __builtin_amdgcn_sched_barrier(0x1 | 0x2 | 0x4 | 0x8);
  };

  for (int it = 0; it < 128; ++it) {
    STEP(hbufA, hbufB, pbuf0, pbuf1);
    STEP(hbufB, hbufA, pbuf1, pbuf0);
  }
}

// ---------------------------------------------------------------------------
extern "C" void kernel_launch(void* const* d_in, const int* in_sizes, int n_in,
                              void* d_out, int out_size, void* d_ws, size_t ws_size,
                              hipStream_t stream) {
  (void)in_sizes; (void)n_in; (void)out_size; (void)ws_size;
  const int* chars        = (const int*)d_in[0];
  const int* left_bichar  = (const int*)d_in[1];
  const int* right_bichar = (const int*)d_in[2];
  const int* extchars     = (const int*)d_in[3];
  const int* extleft      = (const int*)d_in[4];
  const int* extright     = (const int*)d_in[5];
  const int* ctype        = (const int*)d_in[6];
  const float* E_char      = (const float*)d_in[7];
  const float* E_extchar   = (const float*)d_in[8];
  const float* E_bichar    = (const float*)d_in[9];
  const float* E_extbichar = (const float*)d_in[10];
  const float* E_ctype     = (const float*)d_in[11];
  const float* fc_w  = (const float*)d_in[12];
  const float* fc_b  = (const float*)d_in[13];
  const float* Wih_l = (const float*)d_in[14];
  const float* Whh_l = (const float*)d_in[15];
  const float* b_l   = (const float*)d_in[16];
  const float* Wih_r = (const float*)d_in[17];
  const float* Whh_r = (const float*)d_in[18];
  const float* b_r   = (const float*)d_in[19];
  float* out = (float*)d_out;
  char* ws = (char*)d_ws;

  float* x   = (float*)(ws);                        // 13,107,200 B
  float* pre = (float*)(ws + 13107200);             // 52,428,800 B
  unsigned short* fcw_hi = (unsigned short*)(ws + 65536000);   // 186,368
  unsigned short* fcw_lo = (unsigned short*)(ws + 65722368);   // 186,368
  unsigned short* wih_hi = (unsigned short*)(ws + 65908736);   // 716,800
  unsigned short* wih_lo = (unsigned short*)(ws + 66625536);   // 716,800

  presplit_kernel<<<256, 256, 0, stream>>>(fc_w, Wih_l, Wih_r, fcw_hi, fcw_lo, wih_hi, wih_lo);
  fc_kernel<<<512, 256, 0, stream>>>(chars, left_bichar, right_bichar, extchars,
                                     extleft, extright, ctype, E_char, E_extchar,
                                     E_bichar, E_extbichar, E_ctype, fc_b,
                                     fcw_hi, fcw_lo, x);
  xwih_kernel<<<640, 512, 0, stream>>>(x, wih_hi, wih_lo, b_l, b_r, pre);
  lstm_kernel<<<4, 512, 0, stream>>>(pre, Whh_l, Whh_r, out);
}